// Round 1
// baseline (878.637 us; speedup 1.0000x reference)
//
#include <hip/hip_runtime.h>
#include <hip/hip_bf16.h>
#include <cstdint>

#define S_LEN  2048
#define DMODEL 1024
#define NHEAD  8
#define NKV    2
#define HD     128
#define SCALE_F 0.08838834764831845f   // 128^-0.5

// ---------------------------------------------------------------------------
// Effective weight fusion: out[o][i] = w[o][i] + (1/64) * sum_r b[o][r]*a[r][i]
// ---------------------------------------------------------------------------
__global__ __launch_bounds__(256) void fuse_w_kernel(
    const float* __restrict__ w, const float* __restrict__ a,
    const float* __restrict__ b, float* __restrict__ out, int K)
{
  const int i = blockIdx.x * 256 + threadIdx.x;   // column 0..K-1
  const int o = blockIdx.y;                       // row
  const float* br = b + (size_t)o * 64;
  float acc = 0.f;
#pragma unroll 16
  for (int r = 0; r < 64; ++r)
    acc += br[r] * a[(size_t)r * K + i];
  const size_t idx = (size_t)o * K + i;
  out[idx] = w[idx] + acc * 0.015625f;            // 1/R = 1/64
}

// ---------------------------------------------------------------------------
// Y = X @ W^T.  X:[M][K], W:[N][K].  mode 0: Y[M][N] row-major.
// mode 1 (head-major): element (row, col) -> Y[(col>>7)*M*128 + row*128 + (col&127)]
// 64x64 tile, BK=16, 256 threads, 4x4 per thread, k-major LDS ([16][68], 16B-aligned rows)
// ---------------------------------------------------------------------------
__global__ __launch_bounds__(256) void gemm_xwt_kernel(
    const float* __restrict__ X, const float* __restrict__ W,
    float* __restrict__ Y, int M, int N, int K, int headmajor)
{
  __shared__ float Xs[16][68];
  __shared__ float Ws[16][68];
  const int t  = threadIdx.x;
  const int tx = t & 15, ty = t >> 4;
  const int m0 = blockIdx.y * 64, n0 = blockIdx.x * 64;
  const int lr = t >> 2;            // 0..63 tile row for staging
  const int lc = (t & 3) << 2;      // 0,4,8,12 k-offset for staging
  const float* Xp = X + (size_t)(m0 + lr) * K + lc;
  const float* Wp = W + (size_t)(n0 + lr) * K + lc;
  float4 acc0 = {0,0,0,0}, acc1 = {0,0,0,0}, acc2 = {0,0,0,0}, acc3 = {0,0,0,0};

  for (int k0 = 0; k0 < K; k0 += 16) {
    const float4 xa = *(const float4*)(Xp + k0);
    const float4 wa = *(const float4*)(Wp + k0);
    __syncthreads();                 // previous iter's readers done before overwrite
    Xs[lc + 0][lr] = xa.x; Xs[lc + 1][lr] = xa.y; Xs[lc + 2][lr] = xa.z; Xs[lc + 3][lr] = xa.w;
    Ws[lc + 0][lr] = wa.x; Ws[lc + 1][lr] = wa.y; Ws[lc + 2][lr] = wa.z; Ws[lc + 3][lr] = wa.w;
    __syncthreads();
#pragma unroll
    for (int kk = 0; kk < 16; ++kk) {
      const float4 av = *(const float4*)&Xs[kk][ty << 2];
      const float4 bv = *(const float4*)&Ws[kk][tx << 2];
      acc0.x += av.x * bv.x; acc0.y += av.x * bv.y; acc0.z += av.x * bv.z; acc0.w += av.x * bv.w;
      acc1.x += av.y * bv.x; acc1.y += av.y * bv.y; acc1.z += av.y * bv.z; acc1.w += av.y * bv.w;
      acc2.x += av.z * bv.x; acc2.y += av.z * bv.y; acc2.z += av.z * bv.z; acc2.w += av.z * bv.w;
      acc3.x += av.w * bv.x; acc3.y += av.w * bv.y; acc3.z += av.w * bv.z; acc3.w += av.w * bv.w;
    }
  }

  const int col = n0 + (tx << 2);
  const int rowb = m0 + (ty << 2);
  float4 vv[4] = {acc0, acc1, acc2, acc3};
#pragma unroll
  for (int i = 0; i < 4; ++i) {
    const int row = rowb + i;
    if (headmajor) {
      const int hh = col >> 7, dd = col & 127;
      *(float4*)(Y + (((size_t)hh * M + row) << 7) + dd) = vv[i];
    } else {
      *(float4*)(Y + (size_t)row * N + col) = vv[i];
    }
  }
}

// ---------------------------------------------------------------------------
// In-place interleaved RoPE over buf laid out [nh][S][128] (viewed as float2 pairs)
// ---------------------------------------------------------------------------
__global__ __launch_bounds__(256) void rope_kernel(
    float2* __restrict__ buf, const float2* __restrict__ fc,
    const int* __restrict__ sp, int total)
{
  const int p = blockIdx.x * 256 + threadIdx.x;
  if (p >= total) return;
  const int i = p & 63;                   // pair index within head-dim
  const int s = (p >> 6) & (S_LEN - 1);   // sequence position
  const float2 v  = buf[p];
  const float2 cs = fc[(size_t)(sp[0] + s) * 64 + i];
  float2 o;
  o.x = v.x * cs.x - v.y * cs.y;
  o.y = v.x * cs.y + v.y * cs.x;
  buf[p] = o;
}

// ---------------------------------------------------------------------------
// Sparse multi-window attention.
// Q:[8][S][128] (pre-RoPE'd), K,V:[2][S][128]. Out:[S][1024] (s-major, col=h*128+d)
// Nested masks: class A = (k<128 | d<=128) in all 3; B = d in (128,256]; C = (256,512].
// Two passes: (1) running max M + class sums -> Z1..Z3 -> coefficients Ca/Cb/Cc;
// (2) recompute scores, p = exp(s-M)*C_class, PV accumulate.
// Block: 32 queries x 1 head; 256 threads; 32-key tiles.
// ---------------------------------------------------------------------------
__global__ __launch_bounds__(256) void attn_kernel(
    const float* __restrict__ Qb, const float* __restrict__ Kb,
    const float* __restrict__ Vb, const float* __restrict__ swp,
    float* __restrict__ Out)
{
  __shared__ float Qs[32][132];
  __shared__ float Ks[32][132];
  __shared__ float Vs[32][132];
  __shared__ float Ps[32][33];
  __shared__ float Mx[32], Sa[32], Sb[32], Sc[32];
  __shared__ float Ca[32], Cb[32], Cc[32];

  const int t   = threadIdx.x;
  const int h   = blockIdx.y;
  const int q0  = blockIdx.x << 5;
  const int kvh = h >> 2;                 // N_REP = 4
  const float* Qp = Qb + ((size_t)h * S_LEN + q0) * HD;
  const float* Kp = Kb + (size_t)kvh * S_LEN * HD;
  const float* Vp = Vb + (size_t)kvh * S_LEN * HD;

  const int sr = t >> 3;                  // staging row 0..31
  const int sc = (t & 7) << 4;            // staging col 0,16,...,112

  { // stage Q (pre-scaled)
    const float4* s4 = (const float4*)(Qp + sr * HD + sc);
    float4* d4 = (float4*)&Qs[sr][sc];
#pragma unroll
    for (int j = 0; j < 4; ++j) {
      float4 v = s4[j];
      v.x *= SCALE_F; v.y *= SCALE_F; v.z *= SCALE_F; v.w *= SCALE_F;
      d4[j] = v;
    }
  }
  if (t < 32) { Mx[t] = -1e30f; Sa[t] = 0.f; Sb[t] = 0.f; Sc[t] = 0.f; }
  __syncthreads();

  int lo = q0 - 512; if (lo < 0) lo = 0;
  const int hi = min(q0 + 31 + 512, S_LEN - 1);

  const int tq  = t >> 4;                 // 0..15 -> q rows {2tq, 2tq+1}
  const int tk  = t & 15;                 // 0..15 -> k rows {tk, tk+16}
  const int qa  = tq << 1;
  const int qg0 = q0 + qa;

  // ---------------- pass 1: max + class sums ----------------
  for (int k0 = 0; k0 < S_LEN; k0 += 32) {
    if (!((k0 < 128) || (k0 + 32 > lo && k0 <= hi))) continue;
    __syncthreads();
    { // stage K tile
      const float4* s4 = (const float4*)(Kp + (size_t)(k0 + sr) * HD + sc);
      float4* d4 = (float4*)&Ks[sr][sc];
#pragma unroll
      for (int j = 0; j < 4; ++j) d4[j] = s4[j];
    }
    __syncthreads();

    float s00 = 0.f, s01 = 0.f, s10 = 0.f, s11 = 0.f;
#pragma unroll 8
    for (int dd = 0; dd < 32; ++dd) {
      const float4 a0 = *(const float4*)&Qs[qa][dd << 2];
      const float4 a1 = *(const float4*)&Qs[qa + 1][dd << 2];
      const float4 b0 = *(const float4*)&Ks[tk][dd << 2];
      const float4 b1 = *(const float4*)&Ks[tk + 16][dd << 2];
      s00 += a0.x*b0.x + a0.y*b0.y + a0.z*b0.z + a0.w*b0.w;
      s01 += a0.x*b1.x + a0.y*b1.y + a0.z*b1.z + a0.w*b1.w;
      s10 += a1.x*b0.x + a1.y*b0.y + a1.z*b0.z + a1.w*b0.w;
      s11 += a1.x*b1.x + a1.y*b1.y + a1.z*b1.z + a1.w*b1.w;
    }

    const int kg0 = k0 + tk, kg1 = k0 + tk + 16;
#pragma unroll
    for (int i = 0; i < 2; ++i) {
      const int ql = qa + i;
      const int qg = qg0 + i;
      const float sv0 = i ? s10 : s00;
      const float sv1 = i ? s11 : s01;
      int d0 = kg0 - qg; d0 = d0 < 0 ? -d0 : d0;
      int d1 = kg1 - qg; d1 = d1 < 0 ? -d1 : d1;
      const int c0 = (kg0 < 128 || d0 <= 128) ? 0 : (d0 <= 256 ? 1 : (d0 <= 512 ? 2 : 3));
      const int c1 = (kg1 < 128 || d1 <= 128) ? 0 : (d1 <= 256 ? 1 : (d1 <= 512 ? 2 : 3));
      float m_ = -1e30f;
      if (c0 < 3) m_ = sv0;
      if (c1 < 3) m_ = fmaxf(m_, sv1);
#pragma unroll
      for (int msk = 1; msk <= 8; msk <<= 1) m_ = fmaxf(m_, __shfl_xor(m_, msk, 64));
      const float Mold = Mx[ql];
      const float Mnew = fmaxf(Mold, m_);
      const float e0 = (c0 < 3) ? __expf(sv0 - Mnew) : 0.f;
      const float e1 = (c1 < 3) ? __expf(sv1 - Mnew) : 0.f;
      float pA = (c0 == 0 ? e0 : 0.f) + (c1 == 0 ? e1 : 0.f);
      float pB = (c0 == 1 ? e0 : 0.f) + (c1 == 1 ? e1 : 0.f);
      float pC = (c0 == 2 ? e0 : 0.f) + (c1 == 2 ? e1 : 0.f);
#pragma unroll
      for (int msk = 1; msk <= 8; msk <<= 1) {
        pA += __shfl_xor(pA, msk, 64);
        pB += __shfl_xor(pB, msk, 64);
        pC += __shfl_xor(pC, msk, 64);
      }
      if (tk == 0) {                    // one lane per q row updates state
        const float f = __expf(Mold - Mnew);   // safe: Mnew >= Mold, both finite
        Sa[ql] = Sa[ql] * f + pA;
        Sb[ql] = Sb[ql] * f + pB;
        Sc[ql] = Sc[ql] * f + pC;
        Mx[ql] = Mnew;
      }
    }
  }
  __syncthreads();

  // coefficients from nested partition sums
  if (t < 32) {
    const float s0 = swp[0], s1 = swp[1], s2 = swp[2];
    const float mw = fmaxf(s0, fmaxf(s1, s2));
    const float e0 = __expf(s0 - mw), e1 = __expf(s1 - mw), e2 = __expf(s2 - mw);
    const float inv = 1.f / (e0 + e1 + e2);
    const float Z1 = Sa[t], Z2 = Z1 + Sb[t], Z3 = Z2 + Sc[t];
    const float c3 = e2 * inv / Z3;
    const float c2 = e1 * inv / Z2 + c3;
    const float c1 = e0 * inv / Z1 + c2;
    Ca[t] = c1; Cb[t] = c2; Cc[t] = c3;
  }
  // (visibility guaranteed by first __syncthreads in pass-2 loop)

  // ---------------- pass 2: p = exp(s-M)*coef, PV ----------------
  float4 o0 = {0,0,0,0}, o1 = {0,0,0,0}, o2 = {0,0,0,0}, o3 = {0,0,0,0};
  const int qv   = t & 31;
  const int dseg = t >> 5;
  for (int k0 = 0; k0 < S_LEN; k0 += 32) {
    if (!((k0 < 128) || (k0 + 32 > lo && k0 <= hi))) continue;
    __syncthreads();
    { // stage K + V tiles
      const float4* s4 = (const float4*)(Kp + (size_t)(k0 + sr) * HD + sc);
      const float4* v4 = (const float4*)(Vp + (size_t)(k0 + sr) * HD + sc);
      float4* d4 = (float4*)&Ks[sr][sc];
      float4* e4 = (float4*)&Vs[sr][sc];
#pragma unroll
      for (int j = 0; j < 4; ++j) { d4[j] = s4[j]; e4[j] = v4[j]; }
    }
    __syncthreads();

    float s00 = 0.f, s01 = 0.f, s10 = 0.f, s11 = 0.f;
#pragma unroll 8
    for (int dd = 0; dd < 32; ++dd) {
      const float4 a0 = *(const float4*)&Qs[qa][dd << 2];
      const float4 a1 = *(const float4*)&Qs[qa + 1][dd << 2];
      const float4 b0 = *(const float4*)&Ks[tk][dd << 2];
      const float4 b1 = *(const float4*)&Ks[tk + 16][dd << 2];
      s00 += a0.x*b0.x + a0.y*b0.y + a0.z*b0.z + a0.w*b0.w;
      s01 += a0.x*b1.x + a0.y*b1.y + a0.z*b1.z + a0.w*b1.w;
      s10 += a1.x*b0.x + a1.y*b0.y + a1.z*b0.z + a1.w*b0.w;
      s11 += a1.x*b1.x + a1.y*b1.y + a1.z*b1.z + a1.w*b1.w;
    }

    const int kg0 = k0 + tk, kg1 = k0 + tk + 16;
#pragma unroll
    for (int i = 0; i < 2; ++i) {
      const int ql = qa + i;
      const int qg = qg0 + i;
      const float sv0 = i ? s10 : s00;
      const float sv1 = i ? s11 : s01;
      int d0 = kg0 - qg; d0 = d0 < 0 ? -d0 : d0;
      int d1 = kg1 - qg; d1 = d1 < 0 ? -d1 : d1;
      const int c0 = (kg0 < 128 || d0 <= 128) ? 0 : (d0 <= 256 ? 1 : (d0 <= 512 ? 2 : 3));
      const int c1 = (kg1 < 128 || d1 <= 128) ? 0 : (d1 <= 256 ? 1 : (d1 <= 512 ? 2 : 3));
      const float M_ = Mx[ql];
      const float co0 = (c0 == 0) ? Ca[ql] : (c0 == 1) ? Cb[ql] : (c0 == 2) ? Cc[ql] : 0.f;
      const float co1 = (c1 == 0) ? Ca[ql] : (c1 == 1) ? Cb[ql] : (c1 == 2) ? Cc[ql] : 0.f;
      Ps[ql][tk]      = (c0 < 3) ? __expf(sv0 - M_) * co0 : 0.f;
      Ps[ql][tk + 16] = (c1 < 3) ? __expf(sv1 - M_) * co1 : 0.f;
    }
    __syncthreads();

#pragma unroll 8
    for (int k = 0; k < 32; ++k) {
      const float p = Ps[qv][k];
      const float4* vv = (const float4*)&Vs[k][dseg << 4];
      const float4 v0 = vv[0], v1 = vv[1], v2 = vv[2], v3 = vv[3];
      o0.x += p * v0.x; o0.y += p * v0.y; o0.z += p * v0.z; o0.w += p * v0.w;
      o1.x += p * v1.x; o1.y += p * v1.y; o1.z += p * v1.z; o1.w += p * v1.w;
      o2.x += p * v2.x; o2.y += p * v2.y; o2.z += p * v2.z; o2.w += p * v2.w;
      o3.x += p * v3.x; o3.y += p * v3.y; o3.z += p * v3.z; o3.w += p * v3.w;
    }
  }

  float4* op = (float4*)(Out + (size_t)(q0 + qv) * DMODEL + h * HD + (dseg << 4));
  op[0] = o0; op[1] = o1; op[2] = o2; op[3] = o3;
}

// ---------------------------------------------------------------------------
extern "C" void kernel_launch(void* const* d_in, const int* in_sizes, int n_in,
                              void* d_out, int out_size, void* d_ws, size_t ws_size,
                              hipStream_t stream) {
  const float* x    = (const float*)d_in[0];
  const float* fc   = (const float*)d_in[1];
  const float* wq_w = (const float*)d_in[2];
  const float* wq_a = (const float*)d_in[3];
  const float* wq_b = (const float*)d_in[4];
  const float* wk_w = (const float*)d_in[5];
  const float* wk_a = (const float*)d_in[6];
  const float* wk_b = (const float*)d_in[7];
  const float* wv_w = (const float*)d_in[8];
  const float* wv_a = (const float*)d_in[9];
  const float* wv_b = (const float*)d_in[10];
  const float* wo_w = (const float*)d_in[11];
  const float* wo_a = (const float*)d_in[12];
  const float* wo_b = (const float*)d_in[13];
  const float* sw   = (const float*)d_in[14];
  const int*   sp   = (const int*)d_in[15];
  float* out = (float*)d_out;

  // workspace carve-up (floats): ~31.5 MB total
  float* ws = (float*)d_ws;
  float* Wq = ws;                       // 1024*1024
  float* Wk = Wq + 1024 * 1024;         // 256*1024
  float* Wv = Wk + 256 * 1024;          // 256*1024
  float* Wo = Wv + 256 * 1024;          // 1024*1024
  float* Qb = Wo + 1024 * 1024;         // 8*2048*128
  float* Kb = Qb + 8 * 2048 * 128;      // 2*2048*128
  float* Vb = Kb + 2 * 2048 * 128;      // 2*2048*128
  float* AO = Vb + 2 * 2048 * 128;      // 2048*1024

  // 1. fuse LoRA into effective weights
  fuse_w_kernel<<<dim3(4, 1024), 256, 0, stream>>>(wq_w, wq_a, wq_b, Wq, 1024);
  fuse_w_kernel<<<dim3(4, 256),  256, 0, stream>>>(wk_w, wk_a, wk_b, Wk, 1024);
  fuse_w_kernel<<<dim3(4, 256),  256, 0, stream>>>(wv_w, wv_a, wv_b, Wv, 1024);
  fuse_w_kernel<<<dim3(4, 1024), 256, 0, stream>>>(wo_w, wo_a, wo_b, Wo, 1024);

  // 2. QKV projections (head-major outputs)
  gemm_xwt_kernel<<<dim3(16, 32), 256, 0, stream>>>(x, Wq, Qb, 2048, 1024, 1024, 1);
  gemm_xwt_kernel<<<dim3(4, 32),  256, 0, stream>>>(x, Wk, Kb, 2048, 256, 1024, 1);
  gemm_xwt_kernel<<<dim3(4, 32),  256, 0, stream>>>(x, Wv, Vb, 2048, 256, 1024, 1);

  // 3. RoPE (in place) on Q and K
  rope_kernel<<<dim3((8 * 2048 * 64) / 256), 256, 0, stream>>>(
      (float2*)Qb, (const float2*)fc, sp, 8 * 2048 * 64);
  rope_kernel<<<dim3((2 * 2048 * 64) / 256), 256, 0, stream>>>(
      (float2*)Kb, (const float2*)fc, sp, 2 * 2048 * 64);

  // 4. sparse multi-window attention
  attn_kernel<<<dim3(64, 8), 256, 0, stream>>>(Qb, Kb, Vb, sw, AO);

  // 5. output projection
  gemm_xwt_kernel<<<dim3(16, 32), 256, 0, stream>>>(AO, Wo, out, 2048, 1024, 1024, 0);
}

// Round 4
// 339.630 us; speedup vs baseline: 2.5870x; 2.5870x over previous
//
#include <hip/hip_runtime.h>
#include <hip/hip_bf16.h>
#include <cstdint>

#define S_LEN   2048
#define DMODEL  1024
#define NHEAD   8
#define HD      128
// SCALE * log2(e): scores computed in exp2 domain
#define QSCALE  (0.08838834764831845f * 1.4426950408889634f)
#define THR2    11.5416f   // defer-max threshold (8 in ln-domain)

typedef __attribute__((ext_vector_type(8))) short  bf16x8;
typedef __attribute__((ext_vector_type(4))) float  f32x4;

typedef __attribute__((address_space(1))) const unsigned int gu32;
typedef __attribute__((address_space(3))) unsigned int       lu32;

static __device__ __forceinline__ unsigned short f2bf(float x) {
  union { float f; unsigned u; } c; c.f = x;
  unsigned u = c.u + 0x7fff + ((c.u >> 16) & 1);
  return (unsigned short)(u >> 16);
}
static __device__ __forceinline__ f32x4 fz4() {
  f32x4 v; v[0] = 0.f; v[1] = 0.f; v[2] = 0.f; v[3] = 0.f; return v;
}

// ---------------------------------------------------------------------------
// x (fp32) -> bf16
// ---------------------------------------------------------------------------
__global__ __launch_bounds__(256) void xcvt_kernel(
    const float* __restrict__ X, unsigned short* __restrict__ Xb)
{
  const int i = blockIdx.x * 256 + threadIdx.x;       // 4 elems each
  const float4 v = ((const float4*)X)[i];
  ushort4 o;
  o.x = f2bf(v.x); o.y = f2bf(v.y); o.z = f2bf(v.z); o.w = f2bf(v.w);
  ((ushort4*)Xb)[i] = o;
}

// ---------------------------------------------------------------------------
// Effective weight fusion -> bf16: out[o][i] = bf16(w[o][i] + (1/64)*sum_r b[o][r]*a[r][i])
// ---------------------------------------------------------------------------
__global__ __launch_bounds__(256) void fuse_w_kernel(
    const float* __restrict__ w, const float* __restrict__ a,
    const float* __restrict__ b, unsigned short* __restrict__ out)
{
  const int i = blockIdx.x * 256 + threadIdx.x;       // column 0..1023
  const int o = blockIdx.y;                           // row
  const float* br = b + (size_t)o * 64;
  float acc = 0.f;
#pragma unroll 16
  for (int r = 0; r < 64; ++r)
    acc += br[r] * a[(size_t)r * 1024 + i];
  out[(size_t)o * 1024 + i] = f2bf(w[(size_t)o * 1024 + i] + acc * 0.015625f);
}

// ---------------------------------------------------------------------------
// bf16 MFMA GEMM: Y = A @ B^T.  A:[M][K] bf16, B:[N][K] bf16, Y fp32.
// BM=64, BN=128, BK=64. 256 threads = 4 waves; wave tile 32x64.
// LDS double-buffered, staged via global_load_lds(16B) with XOR-swizzled source
// (LDS slot j of a row holds global chunk j^(row&7); reads use the same XOR).
// HEADMAJOR: Y[(col>>7)*M*128 + row*128 + (col&127)]; else row-major [M][N].
// ---------------------------------------------------------------------------
template<int HEADMAJOR>
__global__ __launch_bounds__(256) void gemm_bf16(
    const unsigned short* __restrict__ A, const unsigned short* __restrict__ B,
    float* __restrict__ Y, int M, int N, int K)
{
  __shared__ __align__(16) unsigned short lds[2][(64 + 128) * 64];
  const int t = threadIdx.x;
  const int l = t & 63, wid = t >> 6;
  const int lr = l & 15, lq = l >> 4;
  const int m0 = blockIdx.y * 64, n0 = blockIdx.x * 128;
  const int wm = (wid >> 1) * 32, wn = (wid & 1) * 64;

  f32x4 acc[2][4];
#pragma unroll
  for (int i = 0; i < 2; ++i)
#pragma unroll
    for (int j = 0; j < 4; ++j) acc[i][j] = fz4();

  auto stage = [&](int buf, int k0) {
#pragma unroll
    for (int i = 0; i < 6; ++i) {
      const int ch = wid * 6 + i;
      const unsigned short* src;
      unsigned short* dst;
      int row;
      if (ch < 8) {                       // A rows ch*8..+8
        row = ch * 8 + (l >> 3);
        src = A + (size_t)(m0 + row) * K + k0;
        dst = &lds[buf][ch * 512];
      } else {                            // B rows
        const int bh = ch - 8;
        row = bh * 8 + (l >> 3);
        src = B + (size_t)(n0 + row) * K + k0;
        dst = &lds[buf][4096 + bh * 512];
      }
      const int cg = (l & 7) ^ (row & 7); // pre-swizzled source chunk
      __builtin_amdgcn_global_load_lds((gu32*)(src + cg * 8), (lu32*)dst, 16, 0, 0);
    }
  };

  auto compute = [&](int buf) {
    const unsigned short* la = &lds[buf][0];
    const unsigned short* lb = &lds[buf][4096];
    bf16x8 af[2][2], bfr[4][2];
#pragma unroll
    for (int mi = 0; mi < 2; ++mi)
#pragma unroll
      for (int c = 0; c < 2; ++c) {
        const int row = wm + mi * 16 + lr;
        const int ck = (c * 4 + lq) ^ (row & 7);
        af[mi][c] = *(const bf16x8*)(la + row * 64 + ck * 8);
      }
#pragma unroll
    for (int nj = 0; nj < 4; ++nj)
#pragma unroll
      for (int c = 0; c < 2; ++c) {
        const int row = wn + nj * 16 + lr;
        const int ck = (c * 4 + lq) ^ (row & 7);
        bfr[nj][c] = *(const bf16x8*)(lb + row * 64 + ck * 8);
      }
#pragma unroll
    for (int c = 0; c < 2; ++c)
#pragma unroll
      for (int mi = 0; mi < 2; ++mi)
#pragma unroll
        for (int nj = 0; nj < 4; ++nj)
          acc[mi][nj] = __builtin_amdgcn_mfma_f32_16x16x32_bf16(
              af[mi][c], bfr[nj][c], acc[mi][nj], 0, 0, 0);
  };

  const int NT = K >> 6;
  stage(0, 0);
  int cur = 0;
#pragma unroll 1
  for (int kt = 0; kt < NT; ++kt) {
    __syncthreads();                       // drains vmcnt: staged buf[cur] visible
    if (kt + 1 < NT) stage(cur ^ 1, (kt + 1) << 6);
    compute(cur);
    cur ^= 1;
  }

#pragma unroll
  for (int mi = 0; mi < 2; ++mi)
#pragma unroll
    for (int nj = 0; nj < 4; ++nj)
#pragma unroll
      for (int r = 0; r < 4; ++r) {
        const int row = m0 + wm + mi * 16 + lq * 4 + r;
        const int col = n0 + wn + nj * 16 + lr;
        if (HEADMAJOR)
          Y[(((size_t)(col >> 7) * M + row) << 7) + (col & 127)] = acc[mi][nj][r];
        else
          Y[(size_t)row * N + col] = acc[mi][nj][r];
      }
}

// ---------------------------------------------------------------------------
// RoPE + bf16 convert. QKV fp32 [12][2048][128] head-major.
// Sections 0..7 -> Qb (scaled by QSCALE), 8..9 -> Kb.
// ---------------------------------------------------------------------------
__global__ __launch_bounds__(256) void rope_cvt_kernel(
    const float* __restrict__ QKV, const float* __restrict__ fc,
    const int* __restrict__ sp,
    unsigned short* __restrict__ Qb, unsigned short* __restrict__ Kb)
{
  const int idx = blockIdx.x * 256 + threadIdx.x;  // 10*2048*64
  const int i   = idx & 63;
  const int s   = (idx >> 6) & (S_LEN - 1);
  const int sec = idx >> 17;
  const float2 v  = *(const float2*)(QKV + ((size_t)sec * S_LEN + s) * 128 + 2 * i);
  const float2 cs = *(const float2*)(fc + (size_t)(sp[0] + s) * 128 + 2 * i);
  float xr = v.x * cs.x - v.y * cs.y;
  float yr = v.x * cs.y + v.y * cs.x;
  if (sec < 8) { xr *= QSCALE; yr *= QSCALE; }
  const unsigned w = (unsigned)f2bf(xr) | ((unsigned)f2bf(yr) << 16);
  if (sec < 8)
    ((unsigned*)Qb)[(((size_t)sec * S_LEN + s) * 128 + 2 * i) >> 1] = w;
  else
    ((unsigned*)Kb)[(((size_t)(sec - 8) * S_LEN + s) * 128 + 2 * i) >> 1] = w;
}

// ---------------------------------------------------------------------------
// V transpose: QKV sections 10..11 fp32 [s][d] -> Vt bf16 [kh][d][s]
// ---------------------------------------------------------------------------
__global__ __launch_bounds__(256) void vtrans_kernel(
    const float* __restrict__ QKV, unsigned short* __restrict__ Vt)
{
  const int idx = blockIdx.x * 256 + threadIdx.x;  // 2*128*256
  const int sc8 = idx & 255;
  const int d   = (idx >> 8) & 127;
  const int kh  = idx >> 15;
  const float* src = QKV + ((size_t)(10 + kh) * S_LEN) * 128 + d;
  union { unsigned short u[8]; uint4 v; } o;
#pragma unroll
  for (int j = 0; j < 8; ++j)
    o.u[j] = f2bf(src[(size_t)(sc8 * 8 + j) * 128]);
  *(uint4*)(Vt + ((size_t)kh * 128 + d) * S_LEN + sc8 * 8) = o.v;
}

// ---------------------------------------------------------------------------
// Sparse multi-window attention, bf16 MFMA, single pass.
// One wave per (head, 16 q-rows). K/V read directly from global (L2-resident).
// Classes: A = key<128 | |d|<=128 ; B = |d| in (128,256] ; C = (256,512].
// Three class-partitioned O accumulators; shared running max (exp2 domain,
// defer threshold THR2); combine with nested-Z coefficients at the end.
// Mixed tiles span at most 2 adjacent classes (|d| range width 46 < 128).
// ---------------------------------------------------------------------------
__global__ __launch_bounds__(64, 1) void attn_kernel(
    const unsigned short* __restrict__ Qb,  // [8][2048][128] pre-scaled
    const unsigned short* __restrict__ Kb,  // [2][2048][128]
    const unsigned short* __restrict__ Vt,  // [2][128][2048]
    const float* __restrict__ swp,          // 3 window weights (pre-softmax)
    unsigned short* __restrict__ AO)        // [2048][1024] bf16
{
  __shared__ __align__(16) unsigned short P[512];   // 16 q x 32 k, XOR-swizzled

  const int l  = threadIdx.x;
  const int lr = l & 15, lq = l >> 4;
  const int h  = blockIdx.y;
  const int q0 = blockIdx.x << 4;
  const int kvh = h >> 2;

  const unsigned short* Kp = Kb + (size_t)kvh * S_LEN * 128;
  const unsigned short* Vp = Vt + (size_t)kvh * 128 * S_LEN;

  bf16x8 qf[4];
#pragma unroll
  for (int c = 0; c < 4; ++c)
    qf[c] = *(const bf16x8*)(Qb + ((size_t)(h * S_LEN + q0 + lr)) * 128 + c * 32 + lq * 8);

  f32x4 o0[8], o1[8], o2[8];
#pragma unroll
  for (int i = 0; i < 8; ++i) { o0[i] = fz4(); o1[i] = fz4(); o2[i] = fz4(); }
  float M[4], sA[4], sB[4], sC[4];
#pragma unroll
  for (int r = 0; r < 4; ++r) { M[r] = -1e30f; sA[r] = 0.f; sB[r] = 0.f; sC[r] = 0.f; }

  const int t0w = (q0 >= 512) ? ((q0 - 512) >> 5) : 0;
  const int t1w = min(63, (q0 + 527) >> 5);

#pragma unroll 1
  for (int tt = 0; tt < 64; ++tt) {
    if (!((tt < 4) || (tt >= t0w && tt <= t1w))) continue;
    const int k0 = tt << 5;

    // ---- S = Q K^T (16q x 32k), fp32 acc ----
    f32x4 s0 = fz4(), s1 = fz4();
#pragma unroll
    for (int c = 0; c < 4; ++c) {
      bf16x8 kf0 = *(const bf16x8*)(Kp + (size_t)(k0 + lr) * 128 + c * 32 + lq * 8);
      s0 = __builtin_amdgcn_mfma_f32_16x16x32_bf16(qf[c], kf0, s0, 0, 0, 0);
    }
#pragma unroll
    for (int c = 0; c < 4; ++c) {
      bf16x8 kf1 = *(const bf16x8*)(Kp + (size_t)(k0 + 16 + lr) * 128 + c * 32 + lq * 8);
      s1 = __builtin_amdgcn_mfma_f32_16x16x32_bf16(qf[c], kf1, s1, 0, 0, 0);
    }

    // ---- tile class analysis (wave-uniform) ----
    const int dminT = k0 - (q0 + 15);
    const int dmaxT = k0 + 31 - q0;
    const int aminT = (dminT <= 0 && dmaxT >= 0) ? 0 : min(::abs(dminT), ::abs(dmaxT));
    const int amaxT = max(::abs(dminT), ::abs(dmaxT));
    const int bminT = aminT <= 128 ? 0 : aminT <= 256 ? 1 : aminT <= 512 ? 2 : 3;
    const int bmaxT = amaxT <= 128 ? 0 : amaxT <= 256 ? 1 : amaxT <= 512 ? 2 : 3;
    const bool unifA = (k0 < 128);
    const bool unif  = unifA || (bminT == bmaxT);
    const int  ucls  = unifA ? 0 : bminT;
    if (unif && ucls == 3) continue;

    // ---- per-element classes (mixed tiles only) + tile max ----
    int c0[4], c1[4];
    float mt[4];
#pragma unroll
    for (int r = 0; r < 4; ++r) {
      const float v0 = s0[r], v1 = s1[r];
      if (unif) {
        c0[r] = ucls; c1[r] = ucls;
        mt[r] = fmaxf(v0, v1);
      } else {
        const int q = q0 + lq * 4 + r;
        const int a0 = ::abs(k0 + lr - q);
        const int a1 = ::abs(k0 + 16 + lr - q);
        c0[r] = a0 <= 128 ? 0 : a0 <= 256 ? 1 : a0 <= 512 ? 2 : 3;
        c1[r] = a1 <= 128 ? 0 : a1 <= 256 ? 1 : a1 <= 512 ? 2 : 3;
        mt[r] = fmaxf(c0[r] < 3 ? v0 : -1e30f, c1[r] < 3 ? v1 : -1e30f);
      }
    }
#pragma unroll
    for (int r = 0; r < 4; ++r) {
      mt[r] = fmaxf(mt[r], __shfl_xor(mt[r], 1, 64));
      mt[r] = fmaxf(mt[r], __shfl_xor(mt[r], 2, 64));
      mt[r] = fmaxf(mt[r], __shfl_xor(mt[r], 4, 64));
      mt[r] = fmaxf(mt[r], __shfl_xor(mt[r], 8, 64));
    }

    // ---- online max update (deferred) ----
#pragma unroll
    for (int r = 0; r < 4; ++r) {
      if (mt[r] > M[r] + THR2) {
        const float sc = __builtin_amdgcn_exp2f(M[r] - mt[r]);
        M[r] = mt[r];
        sA[r] *= sc; sB[r] *= sc; sC[r] *= sc;
#pragma unroll
        for (int db = 0; db < 8; ++db) {
          o0[db][r] *= sc; o1[db][r] *= sc; o2[db][r] *= sc;
        }
      }
    }

    // ---- P = exp2(s - M), class sums ----
    float p0[4], p1[4];
#pragma unroll
    for (int r = 0; r < 4; ++r) {
      float e0 = __builtin_amdgcn_exp2f(s0[r] - M[r]);
      float e1 = __builtin_amdgcn_exp2f(s1[r] - M[r]);
      if (!unif) {
        if (c0[r] == 3) e0 = 0.f;
        if (c1[r] == 3) e1 = 0.f;
      }
      p0[r] = e0; p1[r] = e1;
      if (unif) {
        if (ucls == 0)      sA[r] += e0 + e1;
        else if (ucls == 1) sB[r] += e0 + e1;
        else                sC[r] += e0 + e1;
      } else {
        if (c0[r] == 0) sA[r] += e0; else if (c0[r] == 1) sB[r] += e0; else if (c0[r] == 2) sC[r] += e0;
        if (c1[r] == 0) sA[r] += e1; else if (c1[r] == 1) sB[r] += e1; else if (c1[r] == 2) sC[r] += e1;
      }
    }

    // ---- V fragments (global, L2) ----
    bf16x8 vf[8];
#pragma unroll
    for (int db = 0; db < 8; ++db)
      vf[db] = *(const bf16x8*)(Vp + (size_t)(db * 16 + lr) * S_LEN + k0 + lq * 8);

    if (unif) {
#pragma unroll
      for (int r = 0; r < 4; ++r) {
        const int q = lq * 4 + r;
        P[q * 32 + (((lr >> 3) ^ (q & 3)) << 3) + (lr & 7)]        = f2bf(p0[r]);
        P[q * 32 + ((((16 + lr) >> 3) ^ (q & 3)) << 3) + (lr & 7)] = f2bf(p1[r]);
      }
      const bf16x8 pa = *(const bf16x8*)&P[lr * 32 + ((lq ^ (lr & 3)) << 3)];
      if (ucls == 0) {
#pragma unroll
        for (int db = 0; db < 8; ++db)
          o0[db] = __builtin_amdgcn_mfma_f32_16x16x32_bf16(pa, vf[db], o0[db], 0, 0, 0);
      } else if (ucls == 1) {
#pragma unroll
        for (int db = 0; db < 8; ++db)
          o1[db] = __builtin_amdgcn_mfma_f32_16x16x32_bf16(pa, vf[db], o1[db], 0, 0, 0);
      } else {
#pragma unroll
        for (int db = 0; db < 8; ++db)
          o2[db] = __builtin_amdgcn_mfma_f32_16x16x32_bf16(pa, vf[db], o2[db], 0, 0, 0);
      }
    } else {
#pragma unroll 1
      for (int pass = 0; pass < 2; ++pass) {
        const int cc = (pass == 0) ? bminT : bmaxT;
        if (cc == 3) continue;
#pragma unroll
        for (int r = 0; r < 4; ++r) {
          const int q = lq * 4 + r;
          const float u0 = (c0[r] == cc) ? p0[r] : 0.f;
          const float u1 = (c1[r] == cc) ? p1[r] : 0.f;
          P[q * 32 + (((lr >> 3) ^ (q & 3)) << 3) + (lr & 7)]        = f2bf(u0);
          P[q * 32 + ((((16 + lr) >> 3) ^ (q & 3)) << 3) + (lr & 7)] = f2bf(u1);
        }
        const bf16x8 pa = *(const bf16x8*)&P[lr * 32 + ((lq ^ (lr & 3)) << 3)];
        if (cc == 0) {
#pragma unroll
          for (int db = 0; db < 8; ++db)
            o0[db] = __builtin_amdgcn_mfma_f32_16x16x32_bf16(pa, vf[db], o0[db], 0, 0, 0);
        } else if (cc == 1) {
#pragma unroll
          for (int db = 0; db < 8; ++db)
            o1[db] = __builtin_amdgcn_mfma_f32_16x16x32_bf16(pa, vf[db], o1[db], 0, 0, 0);
        } else {
#pragma unroll
          for (int db = 0; db < 8; ++db)
            o2[db] = __builtin_amdgcn_mfma_f32_16x16x32_bf16(pa, vf[db], o2[db], 0, 0, 0);
        }
      }
    }
  }

  // ---- epilogue: reduce class sums, combine, store bf16 ----
#pragma unroll
  for (int r = 0; r < 4; ++r) {
    sA[r] += __shfl_xor(sA[r], 1, 64); sA[r] += __shfl_xor(sA[r], 2, 64);
    sA[r] += __shfl_xor(sA[r], 4, 64); sA[r] += __shfl_xor(sA[r], 8, 64);
    sB[r] += __shfl_xor(sB[r], 1, 64); sB[r] += __shfl_xor(sB[r], 2, 64);
    sB[r] += __shfl_xor(sB[r], 4, 64); sB[r] += __shfl_xor(sB[r], 8, 64);
    sC[r] += __shfl_xor(sC[r], 1, 64); sC[r] += __shfl_xor(sC[r], 2, 64);
    sC[r] += __shfl_xor(sC[r], 4, 64); sC[r] += __shfl_xor(sC[r], 8, 64);
  }
  const float w0 = swp[0], w1 = swp[1], w2 = swp[2];
  const float mw = fmaxf(w0, fmaxf(w1, w2));
  const float e0 = __expf(w0 - mw), e1 = __expf(w1 - mw), e2 = __expf(w2 - mw);
  const float inv = 1.f / (e0 + e1 + e2);
  const float g0 = e0 * inv, g1 = e1 * inv, g2 = e2 * inv;

#pragma unroll
  for (int r = 0; r < 4; ++r) {
    const float Z1 = sA[r], Z2 = Z1 + sB[r], Z3 = Z2 + sC[r];
    const float cC = g2 / Z3;
    const float cB = g1 / Z2 + cC;
    const float cA = g0 / Z1 + cB;
    const int q = q0 + lq * 4 + r;
    unsigned short* dst = AO + (size_t)q * DMODEL + h * HD + lr;
#pragma unroll
    for (int db = 0; db < 8; ++db)
      dst[db * 16] = f2bf(o0[db][r] * cA + o1[db][r] * cB + o2[db][r] * cC);
  }
}

// ---------------------------------------------------------------------------
extern "C" void kernel_launch(void* const* d_in, const int* in_sizes, int n_in,
                              void* d_out, int out_size, void* d_ws, size_t ws_size,
                              hipStream_t stream) {
  const float* x    = (const float*)d_in[0];
  const float* fc   = (const float*)d_in[1];
  const float* wq_w = (const float*)d_in[2];
  const float* wq_a = (const float*)d_in[3];
  const float* wq_b = (const float*)d_in[4];
  const float* wk_w = (const float*)d_in[5];
  const float* wk_a = (const float*)d_in[6];
  const float* wk_b = (const float*)d_in[7];
  const float* wv_w = (const float*)d_in[8];
  const float* wv_a = (const float*)d_in[9];
  const float* wv_b = (const float*)d_in[10];
  const float* wo_w = (const float*)d_in[11];
  const float* wo_a = (const float*)d_in[12];
  const float* wo_b = (const float*)d_in[13];
  const float* sw   = (const float*)d_in[14];
  const int*   sp   = (const int*)d_in[15];
  float* out = (float*)d_out;

  // workspace carve-up (bytes); AO aliases Xbf (dead after QKV GEMM)
  char* wsb = (char*)d_ws;
  unsigned short* Wqkv = (unsigned short*)(wsb + 0);            // 1536*1024*2 = 3 MB
  unsigned short* Wo   = (unsigned short*)(wsb + 3145728);      // 1024*1024*2 = 2 MB
  unsigned short* Xbf  = (unsigned short*)(wsb + 5242880);      // 2048*1024*2 = 4 MB
  float*          QKV  = (float*)(wsb + 9437184);               // 12*2048*128*4 = 12 MB
  unsigned short* Qb   = (unsigned short*)(wsb + 22020096);     // 8*2048*128*2 = 4 MB
  unsigned short* Kb   = (unsigned short*)(wsb + 26214400);     // 1 MB
  unsigned short* Vt   = (unsigned short*)(wsb + 27262976);     // 1 MB
  unsigned short* AO   = (unsigned short*)(wsb + 5242880);      // alias Xbf, 4 MB

  // 1. convert x to bf16; fuse LoRA into effective bf16 weights
  xcvt_kernel<<<2048, 256, 0, stream>>>(x, Xbf);
  fuse_w_kernel<<<dim3(4, 1024), 256, 0, stream>>>(wq_w, wq_a, wq_b, Wqkv);
  fuse_w_kernel<<<dim3(4, 256),  256, 0, stream>>>(wk_w, wk_a, wk_b, Wqkv + 1024 * 1024);
  fuse_w_kernel<<<dim3(4, 256),  256, 0, stream>>>(wv_w, wv_a, wv_b, Wqkv + 1280 * 1024);
  fuse_w_kernel<<<dim3(4, 1024), 256, 0, stream>>>(wo_w, wo_a, wo_b, Wo);

  // 2. fused QKV projection (N=1536), head-major fp32 output
  gemm_bf16<1><<<dim3(12, 32), 256, 0, stream>>>(Xbf, Wqkv, QKV, 2048, 1536, 1024);

  // 3. RoPE + bf16 (Q scaled), V transpose
  rope_cvt_kernel<<<5120, 256, 0, stream>>>(QKV, fc, sp, Qb, Kb);
  vtrans_kernel<<<256, 256, 0, stream>>>(QKV, Vt);

  // 4. sparse multi-window attention (bf16 MFMA, writes AO bf16)
  attn_kernel<<<dim3(128, 8), 64, 0, stream>>>(Qb, Kb, Vt, sw, AO);

  // 5. output projection -> fp32 d_out
  gemm_bf16<0><<<dim3(8, 32), 256, 0, stream>>>(AO, Wo, out, 2048, 1024, 1024);
}

// Round 5
// 221.011 us; speedup vs baseline: 3.9755x; 1.5367x over previous
//
#include <hip/hip_runtime.h>
#include <hip/hip_bf16.h>
#include <cstdint>

#define S_LEN   2048
#define DMODEL  1024
#define NHEAD   8
#define HD      128
// SCALE * log2(e): scores computed in exp2 domain
#define QSCALE  (0.08838834764831845f * 1.4426950408889634f)
#define THR2    11.5416f   // defer-max threshold (8 in ln-domain)

typedef __attribute__((ext_vector_type(8))) short  bf16x8;
typedef __attribute__((ext_vector_type(4))) float  f32x4;

typedef __attribute__((address_space(1))) const unsigned int gu32;
typedef __attribute__((address_space(3))) unsigned int       lu32;

static __device__ __forceinline__ unsigned short f2bf(float x) {
  union { float f; unsigned u; } c; c.f = x;
  unsigned u = c.u + 0x7fff + ((c.u >> 16) & 1);
  return (unsigned short)(u >> 16);
}
static __device__ __forceinline__ f32x4 fz4() {
  f32x4 v; v[0] = 0.f; v[1] = 0.f; v[2] = 0.f; v[3] = 0.f; return v;
}

// ---------------------------------------------------------------------------
// x (fp32) -> bf16
// ---------------------------------------------------------------------------
__global__ __launch_bounds__(256) void xcvt_kernel(
    const float* __restrict__ X, unsigned short* __restrict__ Xb)
{
  const int i = blockIdx.x * 256 + threadIdx.x;       // 4 elems each
  const float4 v = ((const float4*)X)[i];
  ushort4 o;
  o.x = f2bf(v.x); o.y = f2bf(v.y); o.z = f2bf(v.z); o.w = f2bf(v.w);
  ((ushort4*)Xb)[i] = o;
}

// ---------------------------------------------------------------------------
// All four LoRA weight fusions in ONE dispatch.
// Row o of the concatenated [2560][1024] output; b-row staged in LDS;
// float4-vectorized a/w loads. out[o][i] = bf16(w[o][i] + (b@a)[o][i]/64)
// ---------------------------------------------------------------------------
__global__ __launch_bounds__(256) void fuse_all_kernel(
    const float* __restrict__ wq_w, const float* __restrict__ wq_a, const float* __restrict__ wq_b,
    const float* __restrict__ wk_w, const float* __restrict__ wk_a, const float* __restrict__ wk_b,
    const float* __restrict__ wv_w, const float* __restrict__ wv_a, const float* __restrict__ wv_b,
    const float* __restrict__ wo_w, const float* __restrict__ wo_a, const float* __restrict__ wo_b,
    unsigned short* __restrict__ Wqkv, unsigned short* __restrict__ Wo)
{
  __shared__ float bs[64];
  const int t = threadIdx.x;
  const int o = blockIdx.x;
  const float *w, *a, *b; unsigned short* out; int ol;
  if (o < 1024)      { w = wq_w; a = wq_a; b = wq_b; out = Wqkv;              ol = o; }
  else if (o < 1280) { w = wk_w; a = wk_a; b = wk_b; out = Wqkv + 1024*1024;  ol = o - 1024; }
  else if (o < 1536) { w = wv_w; a = wv_a; b = wv_b; out = Wqkv + 1280*1024;  ol = o - 1280; }
  else               { w = wo_w; a = wo_a; b = wo_b; out = Wo;                ol = o - 1536; }
  if (t < 64) bs[t] = b[(size_t)ol * 64 + t];
  __syncthreads();
  float4 acc = {0.f, 0.f, 0.f, 0.f};
#pragma unroll 8
  for (int r = 0; r < 64; ++r) {
    const float4 av = *(const float4*)(a + (size_t)r * 1024 + t * 4);
    const float br = bs[r];
    acc.x += br * av.x; acc.y += br * av.y; acc.z += br * av.z; acc.w += br * av.w;
  }
  const float4 wv = *(const float4*)(w + (size_t)ol * 1024 + t * 4);
  ushort4 ov;
  ov.x = f2bf(wv.x + acc.x * 0.015625f);
  ov.y = f2bf(wv.y + acc.y * 0.015625f);
  ov.z = f2bf(wv.z + acc.z * 0.015625f);
  ov.w = f2bf(wv.w + acc.w * 0.015625f);
  *(ushort4*)(out + (size_t)ol * 1024 + t * 4) = ov;
}

// ---------------------------------------------------------------------------
// bf16 MFMA GEMM: Y = A @ B^T.  A:[M][K] bf16, B:[N][K] bf16, Y fp32.
// BM=64, BN=128, BK=64. 256 threads = 4 waves; wave tile 32x64.
// LDS double-buffered, staged via global_load_lds(16B) with XOR-swizzled source
// (LDS slot j of a row holds global chunk j^(row&7); reads use the same XOR).
// HEADMAJOR: Y[(col>>7)*M*128 + row*128 + (col&127)]; else row-major [M][N].
// ---------------------------------------------------------------------------
template<int HEADMAJOR>
__global__ __launch_bounds__(256) void gemm_bf16(
    const unsigned short* __restrict__ A, const unsigned short* __restrict__ B,
    float* __restrict__ Y, int M, int N, int K)
{
  __shared__ __align__(16) unsigned short lds[2][(64 + 128) * 64];
  const int t = threadIdx.x;
  const int l = t & 63, wid = t >> 6;
  const int lr = l & 15, lq = l >> 4;
  const int m0 = blockIdx.y * 64, n0 = blockIdx.x * 128;
  const int wm = (wid >> 1) * 32, wn = (wid & 1) * 64;

  f32x4 acc[2][4];
#pragma unroll
  for (int i = 0; i < 2; ++i)
#pragma unroll
    for (int j = 0; j < 4; ++j) acc[i][j] = fz4();

  auto stage = [&](int buf, int k0) {
#pragma unroll
    for (int i = 0; i < 6; ++i) {
      const int ch = wid * 6 + i;
      const unsigned short* src;
      unsigned short* dst;
      int row;
      if (ch < 8) {                       // A rows ch*8..+8
        row = ch * 8 + (l >> 3);
        src = A + (size_t)(m0 + row) * K + k0;
        dst = &lds[buf][ch * 512];
      } else {                            // B rows
        const int bh = ch - 8;
        row = bh * 8 + (l >> 3);
        src = B + (size_t)(n0 + row) * K + k0;
        dst = &lds[buf][4096 + bh * 512];
      }
      const int cg = (l & 7) ^ (row & 7); // pre-swizzled source chunk
      __builtin_amdgcn_global_load_lds((gu32*)(src + cg * 8), (lu32*)dst, 16, 0, 0);
    }
  };

  auto compute = [&](int buf) {
    const unsigned short* la = &lds[buf][0];
    const unsigned short* lb = &lds[buf][4096];
    bf16x8 af[2][2], bfr[4][2];
#pragma unroll
    for (int mi = 0; mi < 2; ++mi)
#pragma unroll
      for (int c = 0; c < 2; ++c) {
        const int row = wm + mi * 16 + lr;
        const int ck = (c * 4 + lq) ^ (row & 7);
        af[mi][c] = *(const bf16x8*)(la + row * 64 + ck * 8);
      }
#pragma unroll
    for (int nj = 0; nj < 4; ++nj)
#pragma unroll
      for (int c = 0; c < 2; ++c) {
        const int row = wn + nj * 16 + lr;
        const int ck = (c * 4 + lq) ^ (row & 7);
        bfr[nj][c] = *(const bf16x8*)(lb + row * 64 + ck * 8);
      }
#pragma unroll
    for (int c = 0; c < 2; ++c)
#pragma unroll
      for (int mi = 0; mi < 2; ++mi)
#pragma unroll
        for (int nj = 0; nj < 4; ++nj)
          acc[mi][nj] = __builtin_amdgcn_mfma_f32_16x16x32_bf16(
              af[mi][c], bfr[nj][c], acc[mi][nj], 0, 0, 0);
  };

  const int NT = K >> 6;
  stage(0, 0);
  int cur = 0;
#pragma unroll 1
  for (int kt = 0; kt < NT; ++kt) {
    __syncthreads();                       // drains vmcnt: staged buf[cur] visible
    if (kt + 1 < NT) stage(cur ^ 1, (kt + 1) << 6);
    compute(cur);
    cur ^= 1;
  }

#pragma unroll
  for (int mi = 0; mi < 2; ++mi)
#pragma unroll
    for (int nj = 0; nj < 4; ++nj)
#pragma unroll
      for (int r = 0; r < 4; ++r) {
        const int row = m0 + wm + mi * 16 + lq * 4 + r;
        const int col = n0 + wn + nj * 16 + lr;
        if (HEADMAJOR)
          Y[(((size_t)(col >> 7) * M + row) << 7) + (col & 127)] = acc[mi][nj][r];
        else
          Y[(size_t)row * N + col] = acc[mi][nj][r];
      }
}

// ---------------------------------------------------------------------------
// RoPE + bf16 convert. QKV fp32 [12][2048][128] head-major.
// Sections 0..7 -> Qb (scaled by QSCALE), 8..9 -> Kb.
// ---------------------------------------------------------------------------
__global__ __launch_bounds__(256) void rope_cvt_kernel(
    const float* __restrict__ QKV, const float* __restrict__ fc,
    const int* __restrict__ sp,
    unsigned short* __restrict__ Qb, unsigned short* __restrict__ Kb)
{
  const int idx = blockIdx.x * 256 + threadIdx.x;  // 10*2048*64
  const int i   = idx & 63;
  const int s   = (idx >> 6) & (S_LEN - 1);
  const int sec = idx >> 17;
  const float2 v  = *(const float2*)(QKV + ((size_t)sec * S_LEN + s) * 128 + 2 * i);
  const float2 cs = *(const float2*)(fc + (size_t)(sp[0] + s) * 128 + 2 * i);
  float xr = v.x * cs.x - v.y * cs.y;
  float yr = v.x * cs.y + v.y * cs.x;
  if (sec < 8) { xr *= QSCALE; yr *= QSCALE; }
  const unsigned w = (unsigned)f2bf(xr) | ((unsigned)f2bf(yr) << 16);
  if (sec < 8)
    ((unsigned*)Qb)[(((size_t)sec * S_LEN + s) * 128 + 2 * i) >> 1] = w;
  else
    ((unsigned*)Kb)[(((size_t)(sec - 8) * S_LEN + s) * 128 + 2 * i) >> 1] = w;
}

// ---------------------------------------------------------------------------
// V transpose via LDS tile: QKV sections 10..11 fp32 [s][d] -> Vt bf16 [kh][d][s]
// 64x64 tiles; coalesced global reads and writes.
// ---------------------------------------------------------------------------
__global__ __launch_bounds__(256) void vtrans_kernel(
    const float* __restrict__ QKV, unsigned short* __restrict__ Vt)
{
  __shared__ float T[64][68];
  const int t = threadIdx.x;
  const int b = blockIdx.x;           // 2 kh x 32 s-tiles x 2 d-tiles = 128
  const int dt = b & 1, st = (b >> 1) & 31, kh = b >> 6;
  const int s0 = st * 64, d0 = dt * 64;
  const float* src = QKV + ((size_t)(10 + kh) * S_LEN + s0) * 128 + d0;
  const int row = t >> 4, c4 = (t & 15) * 4;
#pragma unroll
  for (int i = 0; i < 4; ++i) {
    const float4 v = *(const float4*)(src + (size_t)(row + i * 16) * 128 + c4);
    *(float4*)&T[row + i * 16][c4] = v;
  }
  __syncthreads();
  const int dl = t >> 2, s4 = (t & 3) * 16;
  unsigned short* dst = Vt + ((size_t)(kh * 128 + d0 + dl)) * S_LEN + s0 + s4;
#pragma unroll
  for (int half = 0; half < 2; ++half) {
    union { unsigned short u[8]; uint4 q; } o;
#pragma unroll
    for (int jj = 0; jj < 8; ++jj) o.u[jj] = f2bf(T[s4 + half * 8 + jj][dl]);
    *(uint4*)(dst + half * 8) = o.q;
  }
}

// ---------------------------------------------------------------------------
// Sparse multi-window attention, bf16 MFMA, split-K across 2 waves per block.
// Block: 128 threads = 2 waves; each wave owns half the tile list for
// (head h, 16 q-rows). Wave-uniform running max (exp2 domain, __any defer
// test, THR2 slack). 3 class-partitioned O accumulators; cross-wave combine
// via LDS; nested-Z coefficients; LDS-transposed coalesced bf16 store.
// Classes: A = key<128 | |d|<=128 ; B = |d| in (128,256] ; C = (256,512].
// ---------------------------------------------------------------------------
__global__ __launch_bounds__(128, 2) void attn_kernel(
    const unsigned short* __restrict__ Qb,  // [8][2048][128] pre-scaled
    const unsigned short* __restrict__ Kb,  // [2][2048][128]
    const unsigned short* __restrict__ Vt,  // [2][128][2048]
    const float* __restrict__ swp,          // 3 window weights (pre-softmax)
    unsigned short* __restrict__ AO)        // [2048][1024] bf16
{
  __shared__ __align__(16) unsigned short P[2][512];  // per-wave P tile, XOR-swizzled
  __shared__ __align__(16) float OS[6144];            // 24 KB: [3][8][4][64]; reused as OT[16][132]
  __shared__ float ST[3][16];
  __shared__ float MW;

  const int t   = threadIdx.x;
  const int wid = t >> 6;
  const int l   = t & 63;
  const int lr  = l & 15, lq = l >> 4;
  const int h   = blockIdx.y;
  const int q0  = blockIdx.x << 4;
  const int kvh = h >> 2;

  const unsigned short* Kp = Kb + (size_t)kvh * S_LEN * 128;
  const unsigned short* Vp = Vt + (size_t)kvh * 128 * S_LEN;

  bf16x8 qf[4];
#pragma unroll
  for (int c = 0; c < 4; ++c)
    qf[c] = *(const bf16x8*)(Qb + ((size_t)(h * S_LEN + q0 + lr)) * 128 + c * 32 + lq * 8);

  f32x4 o0[8], o1[8], o2[8];
#pragma unroll
  for (int i = 0; i < 8; ++i) { o0[i] = fz4(); o1[i] = fz4(); o2[i] = fz4(); }
  float sA[4], sB[4], sC[4];
#pragma unroll
  for (int r = 0; r < 4; ++r) { sA[r] = 0.f; sB[r] = 0.f; sC[r] = 0.f; }
  float M = -1e30f;                        // wave-uniform running max

  // ---- tile list: [0,4) global prefix  U  [t0w, t1w] window; split in half ----
  const int t0w = (q0 >= 512) ? ((q0 - 512) >> 5) : 0;
  const int t1w = min(63, (q0 + 527) >> 5);
  int nA, base;
  if (t0w < 4) { nA = 0; base = 0; }       // contiguous [0, t1w]
  else         { nA = 4; base = t0w; }
  const int n  = nA + t1w - base + 1;
  const int nh = n >> 1;
  const int jb = wid ? nh : 0;
  const int je = wid ? n  : nh;

#pragma unroll 1
  for (int j = jb; j < je; ++j) {
    const int tt = (j < nA) ? j : (base + j - nA);
    const int k0 = tt << 5;

    // ---- S = Q K^T (16q x 32k), fp32 acc ----
    f32x4 s0 = fz4(), s1 = fz4();
#pragma unroll
    for (int c = 0; c < 4; ++c) {
      bf16x8 kf0 = *(const bf16x8*)(Kp + (size_t)(k0 + lr) * 128 + c * 32 + lq * 8);
      s0 = __builtin_amdgcn_mfma_f32_16x16x32_bf16(qf[c], kf0, s0, 0, 0, 0);
    }
#pragma unroll
    for (int c = 0; c < 4; ++c) {
      bf16x8 kf1 = *(const bf16x8*)(Kp + (size_t)(k0 + 16 + lr) * 128 + c * 32 + lq * 8);
      s1 = __builtin_amdgcn_mfma_f32_16x16x32_bf16(qf[c], kf1, s1, 0, 0, 0);
    }

    // ---- tile class analysis (wave-uniform) ----
    const int dminT = k0 - (q0 + 15);
    const int dmaxT = k0 + 31 - q0;
    const int aminT = (dminT <= 0 && dmaxT >= 0) ? 0 : min(::abs(dminT), ::abs(dmaxT));
    const int amaxT = max(::abs(dminT), ::abs(dmaxT));
    const int bminT = aminT <= 128 ? 0 : aminT <= 256 ? 1 : aminT <= 512 ? 2 : 3;
    const int bmaxT = amaxT <= 128 ? 0 : amaxT <= 256 ? 1 : amaxT <= 512 ? 2 : 3;
    const bool unifA = (k0 < 128);
    const bool unif  = unifA || (bminT == bmaxT);
    const int  ucls  = unifA ? 0 : bminT;

    // ---- deferred wave-uniform max update (__any test; full reduce only on trigger) ----
    float lm = fmaxf(s0[0], s1[0]);
#pragma unroll
    for (int r = 1; r < 4; ++r) lm = fmaxf(lm, fmaxf(s0[r], s1[r]));
    if (__any(lm > M + THR2)) {
      float wm = lm;
      wm = fmaxf(wm, __shfl_xor(wm, 1, 64));
      wm = fmaxf(wm, __shfl_xor(wm, 2, 64));
      wm = fmaxf(wm, __shfl_xor(wm, 4, 64));
      wm = fmaxf(wm, __shfl_xor(wm, 8, 64));
      wm = fmaxf(wm, __shfl_xor(wm, 16, 64));
      wm = fmaxf(wm, __shfl_xor(wm, 32, 64));
      const float Mn = fmaxf(M, wm);
      const float sc = __builtin_amdgcn_exp2f(M - Mn);   // 0 on first trigger
      M = Mn;
#pragma unroll
      for (int r = 0; r < 4; ++r) { sA[r] *= sc; sB[r] *= sc; sC[r] *= sc; }
#pragma unroll
      for (int db = 0; db < 8; ++db) { o0[db] *= sc; o1[db] *= sc; o2[db] *= sc; }
    }

    // ---- P = exp2(s - M), class sums ----
    float p0[4], p1[4];
    int c0[4], c1[4];
#pragma unroll
    for (int r = 0; r < 4; ++r) {
      float e0 = __builtin_amdgcn_exp2f(s0[r] - M);
      float e1 = __builtin_amdgcn_exp2f(s1[r] - M);
      if (unif) {
        c0[r] = ucls; c1[r] = ucls;
        if (ucls == 0)      sA[r] += e0 + e1;
        else if (ucls == 1) sB[r] += e0 + e1;
        else                sC[r] += e0 + e1;
      } else {
        const int q  = q0 + lq * 4 + r;
        const int a0 = ::abs(k0 + lr - q);
        const int a1 = ::abs(k0 + 16 + lr - q);
        c0[r] = a0 <= 128 ? 0 : a0 <= 256 ? 1 : a0 <= 512 ? 2 : 3;
        c1[r] = a1 <= 128 ? 0 : a1 <= 256 ? 1 : a1 <= 512 ? 2 : 3;
        if (c0[r] == 3) e0 = 0.f;
        if (c1[r] == 3) e1 = 0.f;
        if (c0[r] == 0) sA[r] += e0; else if (c0[r] == 1) sB[r] += e0; else if (c0[r] == 2) sC[r] += e0;
        if (c1[r] == 0) sA[r] += e1; else if (c1[r] == 1) sB[r] += e1; else if (c1[r] == 2) sC[r] += e1;
      }
      p0[r] = e0; p1[r] = e1;
    }

    // ---- V fragments (global, L2) ----
    bf16x8 vf[8];
#pragma unroll
    for (int db = 0; db < 8; ++db)
      vf[db] = *(const bf16x8*)(Vp + (size_t)(db * 16 + lr) * S_LEN + k0 + lq * 8);

    if (unif) {
#pragma unroll
      for (int r = 0; r < 4; ++r) {
        const int q = lq * 4 + r;
        P[wid][q * 32 + (((lr >> 3) ^ r) << 3) + (lr & 7)]        = f2bf(p0[r]);
        P[wid][q * 32 + ((((16 + lr) >> 3) ^ r) << 3) + (lr & 7)] = f2bf(p1[r]);
      }
      const bf16x8 pa = *(const bf16x8*)&P[wid][lr * 32 + ((lq ^ (lr & 3)) << 3)];
      if (ucls == 0) {
#pragma unroll
        for (int db = 0; db < 8; ++db)
          o0[db] = __builtin_amdgcn_mfma_f32_16x16x32_bf16(pa, vf[db], o0[db], 0, 0, 0);
      } else if (ucls == 1) {
#pragma unroll
        for (int db = 0; db < 8; ++db)
          o1[db] = __builtin_amdgcn_mfma_f32_16x16x32_bf16(pa, vf[db], o1[db], 0, 0, 0);
      } else {
#pragma unroll
        for (int db = 0; db < 8; ++db)
          o2[db] = __builtin_amdgcn_mfma_f32_16x16x32_bf16(pa, vf[db], o2[db], 0, 0, 0);
      }
    } else {
#pragma unroll 1
      for (int pass = 0; pass < 2; ++pass) {
        const int cc = (pass == 0) ? bminT : bmaxT;
        if (cc == 3) continue;
#pragma unroll
        for (int r = 0; r < 4; ++r) {
          const int q = lq * 4 + r;
          const float u0 = (c0[r] == cc) ? p0[r] : 0.f;
          const float u1 = (c1[r] == cc) ? p1[r] : 0.f;
          P[wid][q * 32 + (((lr >> 3) ^ r) << 3) + (lr & 7)]        = f2bf(u0);
          P[wid][q * 32 + ((((16 + lr) >> 3) ^ r) << 3) + (lr & 7)] = f2bf(u1);
        }
        const bf16x8 pa = *(const bf16x8*)&P[wid][lr * 32 + ((lq ^ (lr & 3)) << 3)];
        if (cc == 0) {
#pragma unroll
          for (int db = 0; db < 8; ++db)
            o0[db] = __builtin_amdgcn_mfma_f32_16x16x32_bf16(pa, vf[db], o0[db], 0, 0, 0);
        } else if (cc == 1) {
#pragma unroll
          for (int db = 0; db < 8; ++db)
            o1[db] = __builtin_amdgcn_mfma_f32_16x16x32_bf16(pa, vf[db], o1[db], 0, 0, 0);
        } else {
#pragma unroll
          for (int db = 0; db < 8; ++db)
            o2[db] = __builtin_amdgcn_mfma_f32_16x16x32_bf16(pa, vf[db], o2[db], 0, 0, 0);
        }
      }
    }
  }

  // ---- per-row sum reduce over the 16 key-lanes ----
#pragma unroll
  for (int r = 0; r < 4; ++r) {
    sA[r] += __shfl_xor(sA[r], 1, 64); sA[r] += __shfl_xor(sA[r], 2, 64);
    sA[r] += __shfl_xor(sA[r], 4, 64); sA[r] += __shfl_xor(sA[r], 8, 64);
    sB[r] += __shfl_xor(sB[r], 1, 64); sB[r] += __shfl_xor(sB[r], 2, 64);
    sB[r] += __shfl_xor(sB[r], 4, 64); sB[r] += __shfl_xor(sB[r], 8, 64);
    sC[r] += __shfl_xor(sC[r], 1, 64); sC[r] += __shfl_xor(sC[r], 2, 64);
    sC[r] += __shfl_xor(sC[r], 4, 64); sC[r] += __shfl_xor(sC[r], 8, 64);
  }

  // ---- cross-wave combine: wave1 -> LDS, wave0 merges ----
  if (wid == 1) {
    if (l == 0) MW = M;
    if (lr == 0) {
#pragma unroll
      for (int r = 0; r < 4; ++r) {
        ST[0][lq * 4 + r] = sA[r];
        ST[1][lq * 4 + r] = sB[r];
        ST[2][lq * 4 + r] = sC[r];
      }
    }
#pragma unroll
    for (int db = 0; db < 8; ++db)
#pragma unroll
      for (int r = 0; r < 4; ++r) {
        OS[((0 * 8 + db) * 4 + r) * 64 + l] = o0[db][r];
        OS[((1 * 8 + db) * 4 + r) * 64 + l] = o1[db][r];
        OS[((2 * 8 + db) * 4 + r) * 64 + l] = o2[db][r];
      }
  }
  __syncthreads();
  if (wid == 1) return;

  {
    const float M1 = MW;
    const float Mn = fmaxf(M, M1);
    const float f0 = __builtin_amdgcn_exp2f(M - Mn);
    const float f1 = __builtin_amdgcn_exp2f(M1 - Mn);
#pragma unroll
    for (int r = 0; r < 4; ++r) {
      sA[r] = f0 * sA[r] + f1 * ST[0][lq * 4 + r];
      sB[r] = f0 * sB[r] + f1 * ST[1][lq * 4 + r];
      sC[r] = f0 * sC[r] + f1 * ST[2][lq * 4 + r];
    }
#pragma unroll
    for (int db = 0; db < 8; ++db)
#pragma unroll
      for (int r = 0; r < 4; ++r) {
        o0[db][r] = f0 * o0[db][r] + f1 * OS[((0 * 8 + db) * 4 + r) * 64 + l];
        o1[db][r] = f0 * o1[db][r] + f1 * OS[((1 * 8 + db) * 4 + r) * 64 + l];
        o2[db][r] = f0 * o2[db][r] + f1 * OS[((2 * 8 + db) * 4 + r) * 64 + l];
      }
  }

  // ---- coefficients from nested partition sums; write to OT (reuses OS) ----
  const float w0 = swp[0], w1 = swp[1], w2 = swp[2];
  const float mw = fmaxf(w0, fmaxf(w1, w2));
  const float e0 = __expf(w0 - mw), e1 = __expf(w1 - mw), e2 = __expf(w2 - mw);
  const float inv = 1.f / (e0 + e1 + e2);
  const float g0 = e0 * inv, g1 = e1 * inv, g2 = e2 * inv;

#pragma unroll
  for (int r = 0; r < 4; ++r) {
    const float Z1 = sA[r], Z2 = Z1 + sB[r], Z3 = Z2 + sC[r];
    const float cC = g2 / Z3;
    const float cB = g1 / Z2 + cC;
    const float cA = g0 / Z1 + cB;
#pragma unroll
    for (int db = 0; db < 8; ++db)
      OS[(lq * 4 + r) * 132 + db * 16 + lr] =
          o0[db][r] * cA + o1[db][r] * cB + o2[db][r] * cC;
  }

  // ---- coalesced bf16 store: lane covers (q = l>>2, d = (l&3)*8 + j*32) ----
  const int qr = l >> 2, dc = (l & 3) * 8;
  unsigned short* dst = AO + (size_t)(q0 + qr) * DMODEL + h * HD + dc;
#pragma unroll
  for (int j = 0; j < 4; ++j) {
    const float4 v0 = *(const float4*)&OS[qr * 132 + dc + j * 32];
    const float4 v1 = *(const float4*)&OS[qr * 132 + dc + j * 32 + 4];
    union { unsigned short u[8]; uint4 q4; } pk;
    pk.u[0] = f2bf(v0.x); pk.u[1] = f2bf(v0.y); pk.u[2] = f2bf(v0.z); pk.u[3] = f2bf(v0.w);
    pk.u[4] = f2bf(v1.x); pk.u[5] = f2bf(v1.y); pk.u[6] = f2bf(v1.z); pk.u[7] = f2bf(v1.w);
    *(uint4*)(dst + j * 32) = pk.q4;
  }
}

// ---------------------------------------------------------------------------
extern "C" void kernel_launch(void* const* d_in, const int* in_sizes, int n_in,
                              void* d_out, int out_size, void* d_ws, size_t ws_size,
                              hipStream_t stream) {
  const float* x    = (const float*)d_in[0];
  const float* fc   = (const float*)d_in[1];
  const float* wq_w = (const float*)d_in[2];
  const float* wq_a = (const float*)d_in[3];
  const float* wq_b = (const float*)d_in[4];
  const float* wk_w = (const float*)d_in[5];
  const float* wk_a = (const float*)d_in[6];
  const float* wk_b = (const float*)d_in[7];
  const float* wv_w = (const float*)d_in[8];
  const float* wv_a = (const float*)d_in[9];
  const float* wv_b = (const float*)d_in[10];
  const float* wo_w = (const float*)d_in[11];
  const float* wo_a = (const float*)d_in[12];
  const float* wo_b = (const float*)d_in[13];
  const float* sw   = (const float*)d_in[14];
  const int*   sp   = (const int*)d_in[15];
  float* out = (float*)d_out;

  // workspace carve-up (bytes); AO aliases Xbf (dead after QKV GEMM)
  char* wsb = (char*)d_ws;
  unsigned short* Wqkv = (unsigned short*)(wsb + 0);            // 1536*1024*2 = 3 MB
  unsigned short* Wo   = (unsigned short*)(wsb + 3145728);      // 1024*1024*2 = 2 MB
  unsigned short* Xbf  = (unsigned short*)(wsb + 5242880);      // 2048*1024*2 = 4 MB
  float*          QKV  = (float*)(wsb + 9437184);               // 12*2048*128*4 = 12 MB
  unsigned short* Qb   = (unsigned short*)(wsb + 22020096);     // 8*2048*128*2 = 4 MB
  unsigned short* Kb   = (unsigned short*)(wsb + 26214400);     // 1 MB
  unsigned short* Vt   = (unsigned short*)(wsb + 27262976);     // 1 MB
  unsigned short* AO   = (unsigned short*)(wsb + 5242880);      // alias Xbf, 4 MB

  // 1. x -> bf16; all LoRA fusions in one dispatch
  xcvt_kernel<<<2048, 256, 0, stream>>>(x, Xbf);
  fuse_all_kernel<<<2560, 256, 0, stream>>>(
      wq_w, wq_a, wq_b, wk_w, wk_a, wk_b, wv_w, wv_a, wv_b, wo_w, wo_a, wo_b,
      Wqkv, Wo);

  // 2. fused QKV projection (N=1536), head-major fp32 output
  gemm_bf16<1><<<dim3(12, 32), 256, 0, stream>>>(Xbf, Wqkv, QKV, 2048, 1536, 1024);

  // 3. RoPE + bf16 (Q scaled); V transpose (LDS tiles)
  rope_cvt_kernel<<<5120, 256, 0, stream>>>(QKV, fc, sp, Qb, Kb);
  vtrans_kernel<<<128, 256, 0, stream>>>(QKV, Vt);

  // 4. sparse multi-window attention (2-wave split-K blocks)
  attn_kernel<<<dim3(128, 8), 128, 0, stream>>>(Qb, Kb, Vt, sw, AO);

  // 5. output projection -> fp32 d_out
  gemm_bf16<0><<<dim3(8, 32), 256, 0, stream>>>(AO, Wo, out, 2048, 1024, 1024);
}